// Round 15
// baseline (177.606 us; speedup 1.0000x reference)
//
#include <hip/hip_runtime.h>
#include <hip/hip_bf16.h>
#include <math.h>
#include <float.h>
#include <stdint.h>

#define N_NODES 10000
#define M_PTS   20000
#define E_EDGES 160000
#define C_CH    128
#define F_CH    128
#define G_GRID  64
#define N_CELLS (G_GRID*G_GRID)
#define NPB     16      // nodes per gemm tile
#define ECAP    64      // max edges stored per node   (Pois(16):  P(>64) ~ 1e-18)
#define CCAP    24      // max points stored per cell  (Pois(2.44): P(>24) ~ 1e-13)
#define A_STRIDE 520    // ushorts per A row: 512 + 8 pad
#define H_STRIDE 136    // ushorts per h1 row: 128 + 8 pad
#define N_TILES (N_NODES / NPB)   // 625 agg tiles
#define W1SZ (4*C_CH*F_CH)        // 65536
#define W2SZ (F_CH*F_CH)          // 16384

typedef __attribute__((ext_vector_type(8))) short short8;
typedef __attribute__((ext_vector_type(4))) float f32x4;

__device__ inline ushort f2bf(float v) {
    __hip_bfloat16 b = __float2bfloat16(v);
    return *reinterpret_cast<ushort*>(&b);
}
__device__ inline float bf2f(ushort u) {
    __hip_bfloat16 b = *reinterpret_cast<__hip_bfloat16*>(&u);
    return __bfloat162float(b);
}
__device__ inline float eluf(float v) { return (v > 0.f) ? v : expm1f(v); }
__device__ inline void insert3(uint64_t key, uint64_t& k0, uint64_t& k1, uint64_t& k2) {
    bool lt2 = key < k2, lt1 = key < k1, lt0 = key < k0;
    k2 = lt1 ? k1 : (lt2 ? key : k2);
    k1 = lt0 ? k0 : (lt1 ? key : k1);
    k0 = lt0 ? key : k0;
}

// ---------- kernel 1: build edge buckets + cell buckets + W transposes ----------
__global__ __launch_bounds__(256) void build_kernel(const int* __restrict__ ei,
    const float* __restrict__ pos, int* __restrict__ ecur, int* __restrict__ ccur,
    int4* __restrict__ edata, int4* __restrict__ cdata,
    const float* __restrict__ Wc, const float* __restrict__ W2,
    ushort* __restrict__ Wct_h, ushort* __restrict__ Wct_l,
    ushort* __restrict__ W2t_h, ushort* __restrict__ W2t_l)
{
    int i = blockIdx.x * 256 + threadIdx.x;
    if (i < E_EDGES) {
        int src = ei[i];
        int dst = ei[E_EDGES + i];
        float dxv = pos[2*dst]     - pos[2*src];
        float dyv = pos[2*dst + 1] - pos[2*src + 1];
        float r2 = dxv*dxv + dyv*dyv;
        float scale = 1.0f / (r2 + 0.01f);
        int slot = atomicAdd(&ecur[dst], 1);
        if (slot < ECAP)
            edata[dst*ECAP + slot] = make_int4(src, __float_as_int(dxv*scale),
                                               __float_as_int(dyv*scale), 0);
    } else if (i < E_EDGES + N_NODES) {
        int j = i - E_EDGES;
        float px = pos[2*j], py = pos[2*j+1];
        int cx = min(max((int)(px * G_GRID), 0), G_GRID - 1);
        int cy = min(max((int)(py * G_GRID), 0), G_GRID - 1);
        int c = cy * G_GRID + cx;
        int slot = atomicAdd(&ccur[c], 1);
        if (slot < CCAP)
            cdata[c*CCAP + slot] = make_int4(__float_as_int(px), __float_as_int(py), j, 0);
    } else if (i < E_EDGES + N_NODES + W1SZ) {
        int j = i - (E_EDGES + N_NODES);        // output index: j = n*512 + k
        int n = j >> 9, k = j & 511;
        float v = Wc[k*F_CH + n];               // scattered L2 read, coalesced write
        ushort h = f2bf(v);
        Wct_h[j] = h;
        Wct_l[j] = f2bf(v - bf2f(h));
    } else if (i < E_EDGES + N_NODES + W1SZ + W2SZ) {
        int j = i - (E_EDGES + N_NODES + W1SZ); // j = n*128 + k
        int n = j >> 7, k = j & 127;
        float v = W2[k*F_CH + n];
        ushort h = f2bf(v);
        W2t_h[j] = h;
        W2t_l[j] = f2bf(v - bf2f(h));
    }
}

// ---------- kernel 2: heterogeneous mega-kernel ----------
// Grid = 785 blocks of 1024. Blocks with bid%5==4 run the knn SEARCH; others run
// the agg+GEMM tile. agg: 16 waves, one node per wave, whole bucket preloaded in
// one wave-wide load, gathers addressed via shuffles, 8 GATHERS IN FLIGHT per
// batch (halved serial round count vs 4-wide). fp64 accumulation => result
// insensitive to bucket order (deterministic). GEMM: waves 0-7, MFMA.
__global__ __launch_bounds__(1024, 8) void mega_kernel(const float* __restrict__ x,
    const int* __restrict__ ecur, const int4* __restrict__ edata,
    const ushort* __restrict__ Wct_h, const ushort* __restrict__ Wct_l,
    const ushort* __restrict__ W2t_h, const ushort* __restrict__ W2t_l,
    const float* __restrict__ bc, const float* __restrict__ b2,
    float* __restrict__ h2out,
    const float* __restrict__ pos_skip, const int* __restrict__ ccur,
    const int4* __restrict__ cdata,
    int* __restrict__ knn_idx, float* __restrict__ knn_w)
{
    __shared__ alignas(16) ushort sA_h[NPB * A_STRIDE];
    __shared__ alignas(16) ushort sA_l[NPB * A_STRIDE];
    __shared__ alignas(16) ushort sH_h[NPB * H_STRIDE];
    __shared__ alignas(16) ushort sH_l[NPB * H_STRIDE];

    const int bid = blockIdx.x;
    const int tid = threadIdx.x;
    const int lane = tid & 63;
    const int wave = tid >> 6;          // 0..15

    if (bid % 5 == 4) {
        // ================= knn search path =================
        int gt = (bid / 5) * 1024 + tid;
        if (gt >= M_PTS * 8) return;
        int t = gt >> 3;
        int sub = gt & 7;
        float tx = pos_skip[2*t], ty = pos_skip[2*t+1];
        const float h = 1.0f / G_GRID;
        int cx = min(max((int)(tx * G_GRID), 0), G_GRID - 1);
        int cy = min(max((int)(ty * G_GRID), 0), G_GRID - 1);

        uint64_t k0 = UINT64_MAX, k1 = UINT64_MAX, k2 = UINT64_MAX;   // own candidates
        uint64_t m0 = UINT64_MAX, m1 = UINT64_MAX, m2 = UINT64_MAX;   // merged

        for (int r = 0; ; r++) {
            if (r >= 2) {     // r=1 bound is 0 — merge there can never trigger a stop
                m0 = k0; m1 = k1; m2 = k2;
                #pragma unroll
                for (int m = 1; m <= 4; m <<= 1) {
                    uint64_t p0 = __shfl_xor((unsigned long long)m0, m, 64);
                    uint64_t p1 = __shfl_xor((unsigned long long)m1, m, 64);
                    uint64_t p2 = __shfl_xor((unsigned long long)m2, m, 64);
                    insert3(p0, m0, m1, m2);
                    insert3(p1, m0, m1, m2);
                    insert3(p2, m0, m1, m2);
                }
                float bound = ((r - 1) * h) * ((r - 1) * h) * 0.99999f;
                float d2cur = __uint_as_float((uint32_t)(m2 >> 32)); // NaN if unset -> no stop
                if (d2cur < bound || r >= G_GRID) break;
            }
            int x0 = max(cx - r, 0), x1 = min(cx + r, G_GRID - 1);
            int y0 = max(cy - r, 0), y1 = min(cy + r, G_GRID - 1);
            int cidx = 0;
            for (int yy = y0; yy <= y1; yy++) {
                bool yedge = (yy == cy - r) || (yy == cy + r);
                for (int xx = x0; xx <= x1; xx++) {
                    if (r > 0 && !yedge && xx != cx - r && xx != cx + r) continue;
                    if ((cidx++ & 7) != sub) continue;
                    int c = yy * G_GRID + xx;
                    int pc = min(ccur[c], CCAP);
                    const int4* cb = cdata + c*CCAP;
                    for (int p = 0; p < pc; p++) {
                        int4 sp = cb[p];
                        float ddx = __fadd_rn(__int_as_float(sp.x), -tx);
                        float ddy = __fadd_rn(__int_as_float(sp.y), -ty);
                        float dd = __fadd_rn(__fmul_rn(ddx, ddx), __fmul_rn(ddy, ddy));
                        uint64_t key = ((uint64_t)__float_as_uint(dd) << 32) | (uint32_t)sp.z;
                        insert3(key, k0, k1, k2);
                    }
                }
            }
        }

        if (sub == 0) {
            float d0 = __uint_as_float((uint32_t)(m0 >> 32));
            float d1 = __uint_as_float((uint32_t)(m1 >> 32));
            float d2 = __uint_as_float((uint32_t)(m2 >> 32));
            float w0 = 1.0f / fmaxf(d0, 1e-16f);
            float w1 = 1.0f / fmaxf(d1, 1e-16f);
            float w2 = 1.0f / fmaxf(d2, 1e-16f);
            float wsum = w0 + w1 + w2;
            knn_idx[t*3+0] = (int)(uint32_t)m0;
            knn_idx[t*3+1] = (int)(uint32_t)m1;
            knn_idx[t*3+2] = (int)(uint32_t)m2;
            knn_w[t*3+0] = w0 / wsum;
            knn_w[t*3+1] = w1 / wsum;
            knn_w[t*3+2] = w2 / wsum;
        }
        return;
    }

    // ================= agg + GEMM path =================
    const int agg_id = bid - bid / 5;
    if (agg_id >= N_TILES) return;
    const int nodeBase = agg_id * NPB;
    const float2* xv = (const float2*)x;

    // ---- phase A: aggregation, one node per wave, 8 gathers in flight ----
    {
        const int rr = wave;
        int node = nodeBase + rr;
        float2 xi = xv[(size_t)node*64 + lane];
        int cnt = ecur[node];
        int m = min(cnt, ECAP);
        int4 er = edata[(size_t)node*ECAP + lane];   // whole bucket in one wave-wide load
        double a1x = 0., a1y = 0., a2x = 0., a2y = 0., a3x = 0., a3y = 0.;
        int p = 0;
        for (; p + 7 < m; p += 8) {
            float2 xg[8];
            #pragma unroll
            for (int q = 0; q < 8; q++) {
                int s = __shfl(er.x, p + q);
                xg[q] = xv[(size_t)s*64 + lane];     // 8 independent gathers in flight
            }
            #pragma unroll
            for (int q = 0; q < 8; q++) {
                float dxe = __int_as_float(__shfl(er.y, p + q));
                float dye = __int_as_float(__shfl(er.z, p + q));
                float vx = xi.x - xg[q].x, vy = xi.y - xg[q].y;
                a1x += (double)(vx*dxe); a1y += (double)(vy*dxe);
                a2x += (double)(vx*dye); a2y += (double)(vy*dye);
                a3x += (double)xg[q].x;  a3y += (double)xg[q].y;
            }
        }
        for (; p < m; p++) {
            int s = __shfl(er.x, p);
            float dxe = __int_as_float(__shfl(er.y, p));
            float dye = __int_as_float(__shfl(er.z, p));
            float2 xj = xv[(size_t)s*64 + lane];
            float vx = xi.x - xj.x, vy = xi.y - xj.y;
            a1x += (double)(vx*dxe); a1y += (double)(vy*dxe);
            a2x += (double)(vx*dye); a2y += (double)(vy*dye);
            a3x += (double)xj.x;     a3y += (double)xj.y;
        }
        float inv = 1.0f / fmaxf((float)cnt, 1.0f);
        float vals[4][2] = {{(float)a1x*inv, (float)a1y*inv},
                            {(float)a2x*inv, (float)a2y*inv},
                            {(float)a3x*inv, (float)a3y*inv},
                            {xi.x, xi.y}};
        int b = rr * A_STRIDE;
        int c0 = 2*lane;
        #pragma unroll
        for (int seg = 0; seg < 4; seg++) {
            ushort hx = f2bf(vals[seg][0]), hy = f2bf(vals[seg][1]);
            ushort lx = f2bf(vals[seg][0] - bf2f(hx)), ly = f2bf(vals[seg][1] - bf2f(hy));
            *(uint*)&sA_h[b + seg*128 + c0] = (uint)hx | ((uint)hy << 16);
            *(uint*)&sA_l[b + seg*128 + c0] = (uint)lx | ((uint)ly << 16);
        }
    }
    __syncthreads();

    // ---- phase G1: h1 = elu(A @ Wc + bc); waves 0-7 cover cols wave*16..+15 ----
    const int col16 = lane & 15;
    const int quad  = lane >> 4;
    const int row   = col16;
    const int ncol  = (wave & 7)*16 + col16;

    if (wave < 8) {
        const float bcv = bc[ncol];
        f32x4 acc = {0,0,0,0};
        for (int ks = 0; ks < 16; ks++) {
            int kb = ks*32 + quad*8;
            short8 ah = *(const short8*)&sA_h[row*A_STRIDE + kb];
            short8 al = *(const short8*)&sA_l[row*A_STRIDE + kb];
            short8 bh = *(const short8*)(Wct_h + (size_t)ncol*512 + kb);
            short8 bl = *(const short8*)(Wct_l + (size_t)ncol*512 + kb);
            acc = __builtin_amdgcn_mfma_f32_16x16x32_bf16(ah, bh, acc, 0, 0, 0);
            acc = __builtin_amdgcn_mfma_f32_16x16x32_bf16(ah, bl, acc, 0, 0, 0);
            acc = __builtin_amdgcn_mfma_f32_16x16x32_bf16(al, bh, acc, 0, 0, 0);
        }
        #pragma unroll
        for (int r = 0; r < 4; r++) {
            int rr = quad*4 + r;
            float v = eluf(acc[r] + bcv);
            ushort hh = f2bf(v);
            sH_h[rr*H_STRIDE + ncol] = hh;
            sH_l[rr*H_STRIDE + ncol] = f2bf(v - bf2f(hh));
        }
    }
    __syncthreads();

    // ---- phase G2: h2 = elu(h1 @ W2 + b2) ----
    if (wave < 8) {
        const float b2v = b2[ncol];
        f32x4 acc2 = {0,0,0,0};
        for (int ks = 0; ks < 4; ks++) {
            int kb = ks*32 + quad*8;
            short8 ah = *(const short8*)&sH_h[row*H_STRIDE + kb];
            short8 al = *(const short8*)&sH_l[row*H_STRIDE + kb];
            short8 bh = *(const short8*)(W2t_h + ncol*128 + kb);
            short8 bl = *(const short8*)(W2t_l + ncol*128 + kb);
            acc2 = __builtin_amdgcn_mfma_f32_16x16x32_bf16(ah, bh, acc2, 0, 0, 0);
            acc2 = __builtin_amdgcn_mfma_f32_16x16x32_bf16(ah, bl, acc2, 0, 0, 0);
            acc2 = __builtin_amdgcn_mfma_f32_16x16x32_bf16(al, bh, acc2, 0, 0, 0);
        }
        #pragma unroll
        for (int r = 0; r < 4; r++) {
            int node = nodeBase + quad*4 + r;
            float v = eluf(acc2[r] + b2v);
            h2out[(size_t)node*F_CH + ncol] = v;
        }
    }
}

// ---------- kernel 3: weighted gather, one wave per target ----------
__global__ __launch_bounds__(256) void gather_kernel(const float* __restrict__ h2,
    const int* __restrict__ knn_idx, const float* __restrict__ knn_w,
    float* __restrict__ out)
{
    int m = blockIdx.x * 4 + (threadIdx.x >> 6);
    int lane = threadIdx.x & 63;
    const float2* h2v = (const float2*)h2;
    int j0 = knn_idx[m*3+0], j1 = knn_idx[m*3+1], j2 = knn_idx[m*3+2];
    float w0 = knn_w[m*3+0], w1 = knn_w[m*3+1], w2 = knn_w[m*3+2];
    float2 a = h2v[(size_t)j0*64 + lane], b = h2v[(size_t)j1*64 + lane], c = h2v[(size_t)j2*64 + lane];
    float2 v;
    v.x = w0*a.x + w1*b.x + w2*c.x;
    v.y = w0*a.y + w1*b.y + w2*c.y;
    ((float2*)out)[(size_t)m*64 + lane] = v;
}

extern "C" void kernel_launch(void* const* d_in, const int* in_sizes, int n_in,
                              void* d_out, int out_size, void* d_ws, size_t ws_size,
                              hipStream_t stream) {
    const float* x        = (const float*)d_in[0];
    const float* pos      = (const float*)d_in[1];
    const float* pos_skip = (const float*)d_in[2];
    const int*   ei       = (const int*)  d_in[3];
    const float* Wc       = (const float*)d_in[4];
    const float* bc       = (const float*)d_in[5];
    const float* W2       = (const float*)d_in[6];
    const float* b2       = (const float*)d_in[7];
    float* out = (float*)d_out;

    char* ws = (char*)d_ws;
    size_t off = 0;
    auto alloc = [&](size_t bytes) {
        void* p = ws + off;
        off = (off + bytes + 255) & ~(size_t)255;
        return p;
    };
    // cursors first & adjacent: one memset covers both
    int*    ecur    = (int*)   alloc((size_t)N_NODES * 4);
    int*    ccur    = (int*)   alloc((size_t)N_CELLS * 4);
    size_t  cur_bytes = (size_t)((char*)ccur - (char*)ecur) + (size_t)N_CELLS * 4;
    int4*   edata   = (int4*)  alloc((size_t)N_NODES * ECAP * 16);
    int4*   cdata   = (int4*)  alloc((size_t)N_CELLS * CCAP * 16);
    float*  h2      = (float*) alloc((size_t)N_NODES * F_CH * 4);
    int*    knn_idx = (int*)   alloc((size_t)M_PTS * 3 * 4);
    float*  knn_w   = (float*) alloc((size_t)M_PTS * 3 * 4);
    ushort* Wct_h   = (ushort*)alloc((size_t)F_CH * 512 * 2);
    ushort* Wct_l   = (ushort*)alloc((size_t)F_CH * 512 * 2);
    ushort* W2t_h   = (ushort*)alloc((size_t)F_CH * 128 * 2);
    ushort* W2t_l   = (ushort*)alloc((size_t)F_CH * 128 * 2);

    hipMemsetAsync(ecur, 0, cur_bytes, stream);
    const int TOT = E_EDGES + N_NODES + W1SZ + W2SZ;
    build_kernel<<<(TOT + 255) / 256, 256, 0, stream>>>(ei, pos, ecur, ccur, edata, cdata,
                                                        Wc, W2, Wct_h, Wct_l, W2t_h, W2t_l);
    mega_kernel<<<785, 1024, 0, stream>>>(x, ecur, edata,
        Wct_h, Wct_l, W2t_h, W2t_l, bc, b2, h2,
        pos_skip, ccur, cdata, knn_idx, knn_w);
    gather_kernel<<<M_PTS / 4, 256, 0, stream>>>(h2, knn_idx, knn_w, out);
}

// Round 16
// 155.680 us; speedup vs baseline: 1.1408x; 1.1408x over previous
//
#include <hip/hip_runtime.h>
#include <hip/hip_bf16.h>
#include <math.h>
#include <float.h>
#include <stdint.h>

#define N_NODES 10000
#define M_PTS   20000
#define E_EDGES 160000
#define C_CH    128
#define F_CH    128
#define G_GRID  64
#define N_CELLS (G_GRID*G_GRID)
#define NPB     16      // nodes per gemm tile
#define ECAP    64      // max edges stored per node   (Pois(16):  P(>64) ~ 1e-18)
#define CCAP    24      // max points stored per cell  (Pois(2.44): P(>24) ~ 1e-13)
#define A_STRIDE 520    // ushorts per A row: 512 + 8 pad
#define H_STRIDE 136    // ushorts per h1 row: 128 + 8 pad
#define N_TILES (N_NODES / NPB)   // 625 agg tiles
#define W1SZ (4*C_CH*F_CH)        // 65536
#define W2SZ (F_CH*F_CH)          // 16384

typedef __attribute__((ext_vector_type(8))) short short8;
typedef __attribute__((ext_vector_type(4))) float f32x4;

__device__ inline ushort f2bf(float v) {
    __hip_bfloat16 b = __float2bfloat16(v);
    return *reinterpret_cast<ushort*>(&b);
}
__device__ inline float bf2f(ushort u) {
    __hip_bfloat16 b = *reinterpret_cast<__hip_bfloat16*>(&u);
    return __bfloat162float(b);
}
__device__ inline float eluf(float v) { return (v > 0.f) ? v : expm1f(v); }
__device__ inline void insert3(uint64_t key, uint64_t& k0, uint64_t& k1, uint64_t& k2) {
    bool lt2 = key < k2, lt1 = key < k1, lt0 = key < k0;
    k2 = lt1 ? k1 : (lt2 ? key : k2);
    k1 = lt0 ? k0 : (lt1 ? key : k1);
    k0 = lt0 ? key : k0;
}

// ---------- kernel 1: build edge buckets + cell buckets + W transposes ----------
__global__ __launch_bounds__(256) void build_kernel(const int* __restrict__ ei,
    const float* __restrict__ pos, int* __restrict__ ecur, int* __restrict__ ccur,
    int4* __restrict__ edata, int4* __restrict__ cdata,
    const float* __restrict__ Wc, const float* __restrict__ W2,
    ushort* __restrict__ Wct_h, ushort* __restrict__ Wct_l,
    ushort* __restrict__ W2t_h, ushort* __restrict__ W2t_l)
{
    int i = blockIdx.x * 256 + threadIdx.x;
    if (i < E_EDGES) {
        int src = ei[i];
        int dst = ei[E_EDGES + i];
        float dxv = pos[2*dst]     - pos[2*src];
        float dyv = pos[2*dst + 1] - pos[2*src + 1];
        float r2 = dxv*dxv + dyv*dyv;
        float scale = 1.0f / (r2 + 0.01f);
        int slot = atomicAdd(&ecur[dst], 1);
        if (slot < ECAP)
            edata[dst*ECAP + slot] = make_int4(src, __float_as_int(dxv*scale),
                                               __float_as_int(dyv*scale), 0);
    } else if (i < E_EDGES + N_NODES) {
        int j = i - E_EDGES;
        float px = pos[2*j], py = pos[2*j+1];
        int cx = min(max((int)(px * G_GRID), 0), G_GRID - 1);
        int cy = min(max((int)(py * G_GRID), 0), G_GRID - 1);
        int c = cy * G_GRID + cx;
        int slot = atomicAdd(&ccur[c], 1);
        if (slot < CCAP)
            cdata[c*CCAP + slot] = make_int4(__float_as_int(px), __float_as_int(py), j, 0);
    } else if (i < E_EDGES + N_NODES + W1SZ) {
        int j = i - (E_EDGES + N_NODES);        // output index: j = n*512 + k
        int n = j >> 9, k = j & 511;
        float v = Wc[k*F_CH + n];               // scattered L2 read, coalesced write
        ushort h = f2bf(v);
        Wct_h[j] = h;
        Wct_l[j] = f2bf(v - bf2f(h));
    } else if (i < E_EDGES + N_NODES + W1SZ + W2SZ) {
        int j = i - (E_EDGES + N_NODES + W1SZ); // j = n*128 + k
        int n = j >> 7, k = j & 127;
        float v = W2[k*F_CH + n];
        ushort h = f2bf(v);
        W2t_h[j] = h;
        W2t_l[j] = f2bf(v - bf2f(h));
    }
}

// ---------- kernel 2: heterogeneous mega-kernel ----------
// Grid = 785 blocks of 1024. Blocks with bid%5==4 run the knn SEARCH (writes
// knn_idx/knn_w, needs only cdata); all others run the agg+GEMM tile (writes h2).
// agg: 16 waves, one node per wave, whole bucket preloaded in one wave-wide load,
// gathers addressed via shuffles, 4 gathers in flight (max that fits the 64-VGPR
// budget of launch_bounds(1024,8) — 8-wide spills to scratch, measured R15).
// fp64 accumulation => result insensitive to bucket order (deterministic).
__global__ __launch_bounds__(1024, 8) void mega_kernel(const float* __restrict__ x,
    const int* __restrict__ ecur, const int4* __restrict__ edata,
    const ushort* __restrict__ Wct_h, const ushort* __restrict__ Wct_l,
    const ushort* __restrict__ W2t_h, const ushort* __restrict__ W2t_l,
    const float* __restrict__ bc, const float* __restrict__ b2,
    float* __restrict__ h2out,
    const float* __restrict__ pos_skip, const int* __restrict__ ccur,
    const int4* __restrict__ cdata,
    int* __restrict__ knn_idx, float* __restrict__ knn_w)
{
    __shared__ alignas(16) ushort sA_h[NPB * A_STRIDE];
    __shared__ alignas(16) ushort sA_l[NPB * A_STRIDE];
    __shared__ alignas(16) ushort sH_h[NPB * H_STRIDE];
    __shared__ alignas(16) ushort sH_l[NPB * H_STRIDE];

    const int bid = blockIdx.x;
    const int tid = threadIdx.x;
    const int lane = tid & 63;
    const int wave = tid >> 6;          // 0..15

    if (bid % 5 == 4) {
        // ================= knn search path =================
        int gt = (bid / 5) * 1024 + tid;
        if (gt >= M_PTS * 8) return;
        int t = gt >> 3;
        int sub = gt & 7;
        float tx = pos_skip[2*t], ty = pos_skip[2*t+1];
        const float h = 1.0f / G_GRID;
        int cx = min(max((int)(tx * G_GRID), 0), G_GRID - 1);
        int cy = min(max((int)(ty * G_GRID), 0), G_GRID - 1);

        uint64_t k0 = UINT64_MAX, k1 = UINT64_MAX, k2 = UINT64_MAX;   // own candidates
        uint64_t m0 = UINT64_MAX, m1 = UINT64_MAX, m2 = UINT64_MAX;   // merged

        for (int r = 0; ; r++) {
            if (r >= 2) {     // r=1 bound is 0 — merge there can never trigger a stop
                m0 = k0; m1 = k1; m2 = k2;
                #pragma unroll
                for (int m = 1; m <= 4; m <<= 1) {
                    uint64_t p0 = __shfl_xor((unsigned long long)m0, m, 64);
                    uint64_t p1 = __shfl_xor((unsigned long long)m1, m, 64);
                    uint64_t p2 = __shfl_xor((unsigned long long)m2, m, 64);
                    insert3(p0, m0, m1, m2);
                    insert3(p1, m0, m1, m2);
                    insert3(p2, m0, m1, m2);
                }
                float bound = ((r - 1) * h) * ((r - 1) * h) * 0.99999f;
                float d2cur = __uint_as_float((uint32_t)(m2 >> 32)); // NaN if unset -> no stop
                if (d2cur < bound || r >= G_GRID) break;
            }
            int x0 = max(cx - r, 0), x1 = min(cx + r, G_GRID - 1);
            int y0 = max(cy - r, 0), y1 = min(cy + r, G_GRID - 1);
            int cidx = 0;
            for (int yy = y0; yy <= y1; yy++) {
                bool yedge = (yy == cy - r) || (yy == cy + r);
                for (int xx = x0; xx <= x1; xx++) {
                    if (r > 0 && !yedge && xx != cx - r && xx != cx + r) continue;
                    if ((cidx++ & 7) != sub) continue;
                    int c = yy * G_GRID + xx;
                    int pc = min(ccur[c], CCAP);
                    const int4* cb = cdata + c*CCAP;
                    for (int p = 0; p < pc; p++) {
                        int4 sp = cb[p];
                        float ddx = __fadd_rn(__int_as_float(sp.x), -tx);
                        float ddy = __fadd_rn(__int_as_float(sp.y), -ty);
                        float dd = __fadd_rn(__fmul_rn(ddx, ddx), __fmul_rn(ddy, ddy));
                        uint64_t key = ((uint64_t)__float_as_uint(dd) << 32) | (uint32_t)sp.z;
                        insert3(key, k0, k1, k2);
                    }
                }
            }
        }

        if (sub == 0) {
            float d0 = __uint_as_float((uint32_t)(m0 >> 32));
            float d1 = __uint_as_float((uint32_t)(m1 >> 32));
            float d2 = __uint_as_float((uint32_t)(m2 >> 32));
            float w0 = 1.0f / fmaxf(d0, 1e-16f);
            float w1 = 1.0f / fmaxf(d1, 1e-16f);
            float w2 = 1.0f / fmaxf(d2, 1e-16f);
            float wsum = w0 + w1 + w2;
            knn_idx[t*3+0] = (int)(uint32_t)m0;
            knn_idx[t*3+1] = (int)(uint32_t)m1;
            knn_idx[t*3+2] = (int)(uint32_t)m2;
            knn_w[t*3+0] = w0 / wsum;
            knn_w[t*3+1] = w1 / wsum;
            knn_w[t*3+2] = w2 / wsum;
        }
        return;
    }

    // ================= agg + GEMM path =================
    const int agg_id = bid - bid / 5;
    if (agg_id >= N_TILES) return;
    const int nodeBase = agg_id * NPB;
    const float2* xv = (const float2*)x;

    // ---- phase A: aggregation, one node per wave, bucket-preload + shuffle addressing ----
    {
        const int rr = wave;
        int node = nodeBase + rr;
        float2 xi = xv[(size_t)node*64 + lane];
        int cnt = ecur[node];
        int m = min(cnt, ECAP);
        int4 er = edata[(size_t)node*ECAP + lane];   // whole bucket in one wave-wide load
        double a1x = 0., a1y = 0., a2x = 0., a2y = 0., a3x = 0., a3y = 0.;
        int p = 0;
        for (; p + 3 < m; p += 4) {
            int s0 = __shfl(er.x, p);     int s1 = __shfl(er.x, p+1);
            int s2 = __shfl(er.x, p+2);   int s3 = __shfl(er.x, p+3);
            float dx0 = __int_as_float(__shfl(er.y, p));
            float dy0 = __int_as_float(__shfl(er.z, p));
            float dx1 = __int_as_float(__shfl(er.y, p+1));
            float dy1 = __int_as_float(__shfl(er.z, p+1));
            float dx2 = __int_as_float(__shfl(er.y, p+2));
            float dy2 = __int_as_float(__shfl(er.z, p+2));
            float dx3 = __int_as_float(__shfl(er.y, p+3));
            float dy3 = __int_as_float(__shfl(er.z, p+3));
            float2 x0 = xv[(size_t)s0*64 + lane];   // 4 independent gathers
            float2 x1 = xv[(size_t)s1*64 + lane];
            float2 x2 = xv[(size_t)s2*64 + lane];
            float2 x3 = xv[(size_t)s3*64 + lane];
            float vx0 = xi.x - x0.x, vy0 = xi.y - x0.y;
            float vx1 = xi.x - x1.x, vy1 = xi.y - x1.y;
            float vx2 = xi.x - x2.x, vy2 = xi.y - x2.y;
            float vx3 = xi.x - x3.x, vy3 = xi.y - x3.y;
            a1x += (double)(vx0*dx0); a1y += (double)(vy0*dx0);
            a2x += (double)(vx0*dy0); a2y += (double)(vy0*dy0);
            a3x += (double)x0.x;      a3y += (double)x0.y;
            a1x += (double)(vx1*dx1); a1y += (double)(vy1*dx1);
            a2x += (double)(vx1*dy1); a2y += (double)(vy1*dy1);
            a3x += (double)x1.x;      a3y += (double)x1.y;
            a1x += (double)(vx2*dx2); a1y += (double)(vy2*dx2);
            a2x += (double)(vx2*dy2); a2y += (double)(vy2*dy2);
            a3x += (double)x2.x;      a3y += (double)x2.y;
            a1x += (double)(vx3*dx3); a1y += (double)(vy3*dx3);
            a2x += (double)(vx3*dy3); a2y += (double)(vy3*dy3);
            a3x += (double)x3.x;      a3y += (double)x3.y;
        }
        for (; p < m; p++) {
            int s = __shfl(er.x, p);
            float dxe = __int_as_float(__shfl(er.y, p));
            float dye = __int_as_float(__shfl(er.z, p));
            float2 xj = xv[(size_t)s*64 + lane];
            float vx = xi.x - xj.x, vy = xi.y - xj.y;
            a1x += (double)(vx*dxe); a1y += (double)(vy*dxe);
            a2x += (double)(vx*dye); a2y += (double)(vy*dye);
            a3x += (double)xj.x;     a3y += (double)xj.y;
        }
        float inv = 1.0f / fmaxf((float)cnt, 1.0f);
        float vals[4][2] = {{(float)a1x*inv, (float)a1y*inv},
                            {(float)a2x*inv, (float)a2y*inv},
                            {(float)a3x*inv, (float)a3y*inv},
                            {xi.x, xi.y}};
        int b = rr * A_STRIDE;
        int c0 = 2*lane;
        #pragma unroll
        for (int seg = 0; seg < 4; seg++) {
            ushort hx = f2bf(vals[seg][0]), hy = f2bf(vals[seg][1]);
            ushort lx = f2bf(vals[seg][0] - bf2f(hx)), ly = f2bf(vals[seg][1] - bf2f(hy));
            *(uint*)&sA_h[b + seg*128 + c0] = (uint)hx | ((uint)hy << 16);
            *(uint*)&sA_l[b + seg*128 + c0] = (uint)lx | ((uint)ly << 16);
        }
    }
    __syncthreads();

    // ---- phase G1: h1 = elu(A @ Wc + bc); waves 0-7 cover cols wave*16..+15 ----
    const int col16 = lane & 15;
    const int quad  = lane >> 4;
    const int row   = col16;
    const int ncol  = (wave & 7)*16 + col16;

    if (wave < 8) {
        const float bcv = bc[ncol];
        f32x4 acc = {0,0,0,0};
        for (int ks = 0; ks < 16; ks++) {
            int kb = ks*32 + quad*8;
            short8 ah = *(const short8*)&sA_h[row*A_STRIDE + kb];
            short8 al = *(const short8*)&sA_l[row*A_STRIDE + kb];
            short8 bh = *(const short8*)(Wct_h + (size_t)ncol*512 + kb);
            short8 bl = *(const short8*)(Wct_l + (size_t)ncol*512 + kb);
            acc = __builtin_amdgcn_mfma_f32_16x16x32_bf16(ah, bh, acc, 0, 0, 0);
            acc = __builtin_amdgcn_mfma_f32_16x16x32_bf16(ah, bl, acc, 0, 0, 0);
            acc = __builtin_amdgcn_mfma_f32_16x16x32_bf16(al, bh, acc, 0, 0, 0);
        }
        #pragma unroll
        for (int r = 0; r < 4; r++) {
            int rr = quad*4 + r;
            float v = eluf(acc[r] + bcv);
            ushort hh = f2bf(v);
            sH_h[rr*H_STRIDE + ncol] = hh;
            sH_l[rr*H_STRIDE + ncol] = f2bf(v - bf2f(hh));
        }
    }
    __syncthreads();

    // ---- phase G2: h2 = elu(h1 @ W2 + b2) ----
    if (wave < 8) {
        const float b2v = b2[ncol];
        f32x4 acc2 = {0,0,0,0};
        for (int ks = 0; ks < 4; ks++) {
            int kb = ks*32 + quad*8;
            short8 ah = *(const short8*)&sH_h[row*H_STRIDE + kb];
            short8 al = *(const short8*)&sH_l[row*H_STRIDE + kb];
            short8 bh = *(const short8*)(W2t_h + ncol*128 + kb);
            short8 bl = *(const short8*)(W2t_l + ncol*128 + kb);
            acc2 = __builtin_amdgcn_mfma_f32_16x16x32_bf16(ah, bh, acc2, 0, 0, 0);
            acc2 = __builtin_amdgcn_mfma_f32_16x16x32_bf16(ah, bl, acc2, 0, 0, 0);
            acc2 = __builtin_amdgcn_mfma_f32_16x16x32_bf16(al, bh, acc2, 0, 0, 0);
        }
        #pragma unroll
        for (int r = 0; r < 4; r++) {
            int node = nodeBase + quad*4 + r;
            float v = eluf(acc2[r] + b2v);
            h2out[(size_t)node*F_CH + ncol] = v;
        }
    }
}

// ---------- kernel 3: weighted gather, one wave per target ----------
__global__ __launch_bounds__(256) void gather_kernel(const float* __restrict__ h2,
    const int* __restrict__ knn_idx, const float* __restrict__ knn_w,
    float* __restrict__ out)
{
    int m = blockIdx.x * 4 + (threadIdx.x >> 6);
    int lane = threadIdx.x & 63;
    const float2* h2v = (const float2*)h2;
    int j0 = knn_idx[m*3+0], j1 = knn_idx[m*3+1], j2 = knn_idx[m*3+2];
    float w0 = knn_w[m*3+0], w1 = knn_w[m*3+1], w2 = knn_w[m*3+2];
    float2 a = h2v[(size_t)j0*64 + lane], b = h2v[(size_t)j1*64 + lane], c = h2v[(size_t)j2*64 + lane];
    float2 v;
    v.x = w0*a.x + w1*b.x + w2*c.x;
    v.y = w0*a.y + w1*b.y + w2*c.y;
    ((float2*)out)[(size_t)m*64 + lane] = v;
}

extern "C" void kernel_launch(void* const* d_in, const int* in_sizes, int n_in,
                              void* d_out, int out_size, void* d_ws, size_t ws_size,
                              hipStream_t stream) {
    const float* x        = (const float*)d_in[0];
    const float* pos      = (const float*)d_in[1];
    const float* pos_skip = (const float*)d_in[2];
    const int*   ei       = (const int*)  d_in[3];
    const float* Wc       = (const float*)d_in[4];
    const float* bc       = (const float*)d_in[5];
    const float* W2       = (const float*)d_in[6];
    const float* b2       = (const float*)d_in[7];
    float* out = (float*)d_out;

    char* ws = (char*)d_ws;
    size_t off = 0;
    auto alloc = [&](size_t bytes) {
        void* p = ws + off;
        off = (off + bytes + 255) & ~(size_t)255;
        return p;
    };
    // cursors first & adjacent: one memset covers both
    int*    ecur    = (int*)   alloc((size_t)N_NODES * 4);
    int*    ccur    = (int*)   alloc((size_t)N_CELLS * 4);
    size_t  cur_bytes = (size_t)((char*)ccur - (char*)ecur) + (size_t)N_CELLS * 4;
    int4*   edata   = (int4*)  alloc((size_t)N_NODES * ECAP * 16);
    int4*   cdata   = (int4*)  alloc((size_t)N_CELLS * CCAP * 16);
    float*  h2      = (float*) alloc((size_t)N_NODES * F_CH * 4);
    int*    knn_idx = (int*)   alloc((size_t)M_PTS * 3 * 4);
    float*  knn_w   = (float*) alloc((size_t)M_PTS * 3 * 4);
    ushort* Wct_h   = (ushort*)alloc((size_t)F_CH * 512 * 2);
    ushort* Wct_l   = (ushort*)alloc((size_t)F_CH * 512 * 2);
    ushort* W2t_h   = (ushort*)alloc((size_t)F_CH * 128 * 2);
    ushort* W2t_l   = (ushort*)alloc((size_t)F_CH * 128 * 2);

    hipMemsetAsync(ecur, 0, cur_bytes, stream);
    const int TOT = E_EDGES + N_NODES + W1SZ + W2SZ;
    build_kernel<<<(TOT + 255) / 256, 256, 0, stream>>>(ei, pos, ecur, ccur, edata, cdata,
                                                        Wc, W2, Wct_h, Wct_l, W2t_h, W2t_l);
    mega_kernel<<<785, 1024, 0, stream>>>(x, ecur, edata,
        Wct_h, Wct_l, W2t_h, W2t_l, bc, b2, h2,
        pos_skip, ccur, cdata, knn_idx, knn_w);
    gather_kernel<<<M_PTS / 4, 256, 0, stream>>>(h2, knn_idx, knn_w, out);
}